// Round 3
// baseline (426.609 us; speedup 1.0000x reference)
//
#include <hip/hip_runtime.h>

// FEM Tri3 integrate, factorized:
//   out[v] = sum_e detJ(e)/6 * (vals[n0][v]+vals[n1][v]+vals[n2][v])
//          = sum_node vals[node][v] * w_node
//   w_node = sum over (element,corner) incidences of detJ(e)/6
// Pass 1: stream elements (nontemporal), gather coords (8 MB table),
//         scatter wdet via atomics into w_node (4 MB, fits per-XCD L2).
// Pass 2: fully-coalesced streaming weighted reduction over nodal_values.

#define NVALS 8

// clang-native vector types: __builtin_nontemporal_load rejects HIP_vector_type.
typedef int   vint4   __attribute__((ext_vector_type(4)));
typedef float vfloat4 __attribute__((ext_vector_type(4)));

__global__ __launch_bounds__(256) void pass1_wdet_scatter(
    const float* __restrict__ coords,    // (N, 2)
    const int*   __restrict__ elements,  // (E, 3)
    float* __restrict__ w_node,          // (N,) pre-zeroed
    int E)
{
    const long long t = blockIdx.x * (long long)blockDim.x + threadIdx.x;
    const long long base = 4LL * t;
    if (base >= E) return;

    if (base + 4 <= E) {
        // 4 consecutive elements = 12 ints = 3 aligned int4 loads (byte offset 48*t).
        const vint4* ep = (const vint4*)elements;
        const vint4 i0 = __builtin_nontemporal_load(ep + 3 * t + 0);
        const vint4 i1 = __builtin_nontemporal_load(ep + 3 * t + 1);
        const vint4 i2 = __builtin_nontemporal_load(ep + 3 * t + 2);
        const int n[12] = {i0.x, i0.y, i0.z, i0.w,
                           i1.x, i1.y, i1.z, i1.w,
                           i2.x, i2.y, i2.z, i2.w};
        float2 c[12];
#pragma unroll
        for (int k = 0; k < 12; ++k)
            c[k] = *(const float2*)(coords + 2 * (size_t)n[k]);
#pragma unroll
        for (int q = 0; q < 4; ++q) {
            const float2 c0 = c[3 * q], c1 = c[3 * q + 1], c2 = c[3 * q + 2];
            const float j00 = c1.x - c0.x, j01 = c1.y - c0.y;
            const float j10 = c2.x - c0.x, j11 = c2.y - c0.y;
            const float wdet = (j00 * j11 - j01 * j10) * (1.0f / 6.0f);
            atomicAdd(&w_node[n[3 * q + 0]], wdet);
            atomicAdd(&w_node[n[3 * q + 1]], wdet);
            atomicAdd(&w_node[n[3 * q + 2]], wdet);
        }
    } else {
        for (long long e = base; e < E; ++e) {
            const int n0 = elements[3 * e + 0];
            const int n1 = elements[3 * e + 1];
            const int n2 = elements[3 * e + 2];
            const float2 c0 = *(const float2*)(coords + 2 * (size_t)n0);
            const float2 c1 = *(const float2*)(coords + 2 * (size_t)n1);
            const float2 c2 = *(const float2*)(coords + 2 * (size_t)n2);
            const float j00 = c1.x - c0.x, j01 = c1.y - c0.y;
            const float j10 = c2.x - c0.x, j11 = c2.y - c0.y;
            const float wdet = (j00 * j11 - j01 * j10) * (1.0f / 6.0f);
            atomicAdd(&w_node[n0], wdet);
            atomicAdd(&w_node[n1], wdet);
            atomicAdd(&w_node[n2], wdet);
        }
    }
}

__global__ __launch_bounds__(256) void pass2_weighted_sum(
    const float* __restrict__ nodal_values,  // (N, 8)
    const float* __restrict__ w_node,        // (N,)
    float* __restrict__ out,                 // (8,) pre-zeroed
    int N)
{
    float acc[NVALS];
#pragma unroll
    for (int v = 0; v < NVALS; ++v) acc[v] = 0.0f;

    const int stride = gridDim.x * blockDim.x;
    for (int n = blockIdx.x * blockDim.x + threadIdx.x; n < N; n += stride) {
        const float w = w_node[n];
        const vfloat4* p = (const vfloat4*)(nodal_values + 8 * (size_t)n);
        const vfloat4 a = __builtin_nontemporal_load(p + 0);
        const vfloat4 b = __builtin_nontemporal_load(p + 1);
        acc[0] = fmaf(w, a.x, acc[0]);
        acc[1] = fmaf(w, a.y, acc[1]);
        acc[2] = fmaf(w, a.z, acc[2]);
        acc[3] = fmaf(w, a.w, acc[3]);
        acc[4] = fmaf(w, b.x, acc[4]);
        acc[5] = fmaf(w, b.y, acc[5]);
        acc[6] = fmaf(w, b.z, acc[6]);
        acc[7] = fmaf(w, b.w, acc[7]);
    }

#pragma unroll
    for (int v = 0; v < NVALS; ++v) {
        float x = acc[v];
        for (int off = 32; off > 0; off >>= 1) x += __shfl_down(x, off, 64);
        acc[v] = x;
    }

    __shared__ float s[4][NVALS];
    const int lane = threadIdx.x & 63;
    const int wave = threadIdx.x >> 6;
    if (lane == 0) {
#pragma unroll
        for (int v = 0; v < NVALS; ++v) s[wave][v] = acc[v];
    }
    __syncthreads();

    if (threadIdx.x < NVALS) {
        const float x = s[0][threadIdx.x] + s[1][threadIdx.x] +
                        s[2][threadIdx.x] + s[3][threadIdx.x];
        atomicAdd(&out[threadIdx.x], x);
    }
}

// Fallback single-pass kernel (used only if ws_size is too small for w_node).
__global__ __launch_bounds__(256) void fem_integrate_fallback(
    const float* __restrict__ nodal_values,
    const float* __restrict__ coords,
    const int*   __restrict__ elements,
    float* __restrict__ out,
    int E)
{
    float acc[NVALS];
#pragma unroll
    for (int v = 0; v < NVALS; ++v) acc[v] = 0.0f;
    const int stride = gridDim.x * blockDim.x;
    for (int e = blockIdx.x * blockDim.x + threadIdx.x; e < E; e += stride) {
        const int n0 = elements[3 * e + 0];
        const int n1 = elements[3 * e + 1];
        const int n2 = elements[3 * e + 2];
        const float2 c0 = *(const float2*)(coords + 2 * (size_t)n0);
        const float2 c1 = *(const float2*)(coords + 2 * (size_t)n1);
        const float2 c2 = *(const float2*)(coords + 2 * (size_t)n2);
        const float j00 = c1.x - c0.x, j01 = c1.y - c0.y;
        const float j10 = c2.x - c0.x, j11 = c2.y - c0.y;
        const float wdet = (j00 * j11 - j01 * j10) * (1.0f / 6.0f);
        const float4* p0 = (const float4*)(nodal_values + 8 * (size_t)n0);
        const float4* p1 = (const float4*)(nodal_values + 8 * (size_t)n1);
        const float4* p2 = (const float4*)(nodal_values + 8 * (size_t)n2);
        const float4 a0 = p0[0], b0 = p0[1];
        const float4 a1 = p1[0], b1 = p1[1];
        const float4 a2 = p2[0], b2 = p2[1];
        acc[0] = fmaf(wdet, a0.x + a1.x + a2.x, acc[0]);
        acc[1] = fmaf(wdet, a0.y + a1.y + a2.y, acc[1]);
        acc[2] = fmaf(wdet, a0.z + a1.z + a2.z, acc[2]);
        acc[3] = fmaf(wdet, a0.w + a1.w + a2.w, acc[3]);
        acc[4] = fmaf(wdet, b0.x + b1.x + b2.x, acc[4]);
        acc[5] = fmaf(wdet, b0.y + b1.y + b2.y, acc[5]);
        acc[6] = fmaf(wdet, b0.z + b1.z + b2.z, acc[6]);
        acc[7] = fmaf(wdet, b0.w + b1.w + b2.w, acc[7]);
    }
#pragma unroll
    for (int v = 0; v < NVALS; ++v) {
        float x = acc[v];
        for (int off = 32; off > 0; off >>= 1) x += __shfl_down(x, off, 64);
        acc[v] = x;
    }
    __shared__ float s[4][NVALS];
    const int lane = threadIdx.x & 63;
    const int wave = threadIdx.x >> 6;
    if (lane == 0) {
#pragma unroll
        for (int v = 0; v < NVALS; ++v) s[wave][v] = acc[v];
    }
    __syncthreads();
    if (threadIdx.x < NVALS) {
        const float x = s[0][threadIdx.x] + s[1][threadIdx.x] +
                        s[2][threadIdx.x] + s[3][threadIdx.x];
        atomicAdd(&out[threadIdx.x], x);
    }
}

extern "C" void kernel_launch(void* const* d_in, const int* in_sizes, int n_in,
                              void* d_out, int out_size, void* d_ws, size_t ws_size,
                              hipStream_t stream) {
    const float* nodal_values = (const float*)d_in[0];  // (N, 8)
    const float* coords       = (const float*)d_in[1];  // (N, 2)
    const int*   elements     = (const int*)d_in[2];    // (E, 3)
    float* out = (float*)d_out;

    const int N = in_sizes[1] / 2;
    const int E = in_sizes[2] / 3;

    (void)hipMemsetAsync(out, 0, out_size * sizeof(float), stream);

    if (ws_size >= (size_t)N * sizeof(float)) {
        float* w_node = (float*)d_ws;
        (void)hipMemsetAsync(w_node, 0, (size_t)N * sizeof(float), stream);

        // Pass 1: 4 elements per thread.
        const long long threads_needed = ((long long)E + 3) / 4;
        const int blocks1 = (int)((threads_needed + 255) / 256);
        pass1_wdet_scatter<<<blocks1, 256, 0, stream>>>(coords, elements,
                                                        w_node, E);

        // Pass 2: streaming weighted reduction.
        pass2_weighted_sum<<<2048, 256, 0, stream>>>(nodal_values, w_node,
                                                     out, N);
    } else {
        fem_integrate_fallback<<<2048, 256, 0, stream>>>(nodal_values, coords,
                                                         elements, out, E);
    }
}

// Round 4
// 264.627 us; speedup vs baseline: 1.6121x; 1.6121x over previous
//
#include <hip/hip_runtime.h>

// FEM Tri3 integrate: out[v] = sum_e detJ(e)/6 * (vals[n0][v]+vals[n1][v]+vals[n2][v])
// (sum_q N_q[q,n] == 1, w_q == 1/6 -> quadrature collapses exactly).
// Single-pass gather+reduce. R3 showed scatter-atomics to w_node are 1.7x
// WORSE (device-scope atomic RMW traffic); R1 single-pass @179us had VGPR=24
// -> low MLP. This version: 4 elements/thread, all ~36 gathers issued in one
// unrolled batch for max memory-level parallelism.

#define NVALS 8

typedef int   vint4   __attribute__((ext_vector_type(4)));
typedef float vfloat4 __attribute__((ext_vector_type(4)));

__global__ __launch_bounds__(256) void fem_integrate_batched(
    const float* __restrict__ nodal_values,  // (N, 8)
    const float* __restrict__ coords,        // (N, 2)
    const int*   __restrict__ elements,      // (E, 3)
    float* __restrict__ out,                 // (8,) pre-zeroed
    int E)
{
    float acc[NVALS];
#pragma unroll
    for (int v = 0; v < NVALS; ++v) acc[v] = 0.0f;

    const long long t = blockIdx.x * 256LL + threadIdx.x;
    const long long base = 4LL * t;

    if (base + 4 <= E) {
        // 4 consecutive elements = 12 ints = 3 aligned int4 loads (48 B @ 48*t).
        const vint4* ep = (const vint4*)elements;
        const vint4 i0 = __builtin_nontemporal_load(ep + 3 * t + 0);
        const vint4 i1 = __builtin_nontemporal_load(ep + 3 * t + 1);
        const vint4 i2 = __builtin_nontemporal_load(ep + 3 * t + 2);
        const int n[12] = {i0.x, i0.y, i0.z, i0.w,
                           i1.x, i1.y, i1.z, i1.w,
                           i2.x, i2.y, i2.z, i2.w};

        // Issue all 12 coord gathers.
        float2 c[12];
#pragma unroll
        for (int k = 0; k < 12; ++k)
            c[k] = *(const float2*)(coords + 2 * (size_t)n[k]);

        // Per-corner value-row sums (24 float4 gathers), fully unrolled so the
        // compiler can keep many loads outstanding.
        vfloat4 sa[4], sb[4];
#pragma unroll
        for (int q = 0; q < 4; ++q) {
            const vfloat4* p0 = (const vfloat4*)(nodal_values + 8 * (size_t)n[3 * q + 0]);
            const vfloat4* p1 = (const vfloat4*)(nodal_values + 8 * (size_t)n[3 * q + 1]);
            const vfloat4* p2 = (const vfloat4*)(nodal_values + 8 * (size_t)n[3 * q + 2]);
            const vfloat4 a0 = p0[0], b0 = p0[1];
            const vfloat4 a1 = p1[0], b1 = p1[1];
            const vfloat4 a2 = p2[0], b2 = p2[1];
            sa[q] = a0 + a1 + a2;
            sb[q] = b0 + b1 + b2;
        }

#pragma unroll
        for (int q = 0; q < 4; ++q) {
            const float2 c0 = c[3 * q], c1 = c[3 * q + 1], c2 = c[3 * q + 2];
            const float j00 = c1.x - c0.x, j01 = c1.y - c0.y;
            const float j10 = c2.x - c0.x, j11 = c2.y - c0.y;
            const float wdet = (j00 * j11 - j01 * j10) * (1.0f / 6.0f);
            acc[0] = fmaf(wdet, sa[q].x, acc[0]);
            acc[1] = fmaf(wdet, sa[q].y, acc[1]);
            acc[2] = fmaf(wdet, sa[q].z, acc[2]);
            acc[3] = fmaf(wdet, sa[q].w, acc[3]);
            acc[4] = fmaf(wdet, sb[q].x, acc[4]);
            acc[5] = fmaf(wdet, sb[q].y, acc[5]);
            acc[6] = fmaf(wdet, sb[q].z, acc[6]);
            acc[7] = fmaf(wdet, sb[q].w, acc[7]);
        }
    } else if (base < E) {
        // Tail (last block only).
        for (long long e = base; e < E; ++e) {
            const int n0 = elements[3 * e + 0];
            const int n1 = elements[3 * e + 1];
            const int n2 = elements[3 * e + 2];
            const float2 c0 = *(const float2*)(coords + 2 * (size_t)n0);
            const float2 c1 = *(const float2*)(coords + 2 * (size_t)n1);
            const float2 c2 = *(const float2*)(coords + 2 * (size_t)n2);
            const float j00 = c1.x - c0.x, j01 = c1.y - c0.y;
            const float j10 = c2.x - c0.x, j11 = c2.y - c0.y;
            const float wdet = (j00 * j11 - j01 * j10) * (1.0f / 6.0f);
            const vfloat4* p0 = (const vfloat4*)(nodal_values + 8 * (size_t)n0);
            const vfloat4* p1 = (const vfloat4*)(nodal_values + 8 * (size_t)n1);
            const vfloat4* p2 = (const vfloat4*)(nodal_values + 8 * (size_t)n2);
            const vfloat4 va = p0[0] + p1[0] + p2[0];
            const vfloat4 vb = p0[1] + p1[1] + p2[1];
            acc[0] = fmaf(wdet, va.x, acc[0]);
            acc[1] = fmaf(wdet, va.y, acc[1]);
            acc[2] = fmaf(wdet, va.z, acc[2]);
            acc[3] = fmaf(wdet, va.w, acc[3]);
            acc[4] = fmaf(wdet, vb.x, acc[4]);
            acc[5] = fmaf(wdet, vb.y, acc[5]);
            acc[6] = fmaf(wdet, vb.z, acc[6]);
            acc[7] = fmaf(wdet, vb.w, acc[7]);
        }
    }
    // Threads with base >= E fall through with acc = 0 and join the reduction.

    // Wave (64-lane) shuffle reduction.
#pragma unroll
    for (int v = 0; v < NVALS; ++v) {
        float x = acc[v];
        for (int off = 32; off > 0; off >>= 1) x += __shfl_down(x, off, 64);
        acc[v] = x;
    }

    __shared__ float s[4][NVALS];
    const int lane = threadIdx.x & 63;
    const int wave = threadIdx.x >> 6;
    if (lane == 0) {
#pragma unroll
        for (int v = 0; v < NVALS; ++v) s[wave][v] = acc[v];
    }
    __syncthreads();

    if (threadIdx.x < NVALS) {
        const float x = s[0][threadIdx.x] + s[1][threadIdx.x] +
                        s[2][threadIdx.x] + s[3][threadIdx.x];
        atomicAdd(&out[threadIdx.x], x);
    }
}

extern "C" void kernel_launch(void* const* d_in, const int* in_sizes, int n_in,
                              void* d_out, int out_size, void* d_ws, size_t ws_size,
                              hipStream_t stream) {
    const float* nodal_values = (const float*)d_in[0];  // (N, 8)
    const float* coords       = (const float*)d_in[1];  // (N, 2)
    const int*   elements     = (const int*)d_in[2];    // (E, 3)
    float* out = (float*)d_out;

    const int E = in_sizes[2] / 3;

    (void)hipMemsetAsync(out, 0, out_size * sizeof(float), stream);

    // One thread per 4 elements, no grid-stride: E=2e6 -> 512K threads -> 2048 blocks.
    const long long threads_needed = ((long long)E + 3) / 4;
    const int blocks = (int)((threads_needed + 255) / 256);
    fem_integrate_batched<<<blocks, 256, 0, stream>>>(nodal_values, coords,
                                                      elements, out, E);
}

// Round 5
// 236.340 us; speedup vs baseline: 1.8051x; 1.1197x over previous
//
#include <hip/hip_runtime.h>

// FEM Tri3 integrate: out[v] = sum_e detJ(e)/6 * (vals[n0][v]+vals[n1][v]+vals[n2][v])
// R1/R4 established: random-gather fill traffic (~655 MB) at ~3.7 TB/s is the
// limiter; MLP doesn't help; scatter atomics are worse. This round: quantize
// gather tables to fp16 in ws (threshold 3.62 allows it):
//   coords 8MB->4MB (== per-XCD L2, near-resident), values 32MB->16MB
//   (16 B rows -> 4 rows per 64 B line -> ~2x hit rate).

#define NVALS 8

typedef float    vfloat4 __attribute__((ext_vector_type(4)));
typedef _Float16 vhalf2  __attribute__((ext_vector_type(2)));
typedef _Float16 vhalf8  __attribute__((ext_vector_type(8)));

__global__ __launch_bounds__(256) void convert_fp16(
    const float* __restrict__ coords,   // (N,2)
    const float* __restrict__ vals,     // (N,8)
    vhalf2* __restrict__ c16,           // (N,)
    vhalf8* __restrict__ v16,           // (N,)
    int N)
{
    const int i = blockIdx.x * 256 + threadIdx.x;
    if (i >= N) return;
    const float2 c = *(const float2*)(coords + 2 * (size_t)i);
    vhalf2 h;
    h.x = (_Float16)c.x;
    h.y = (_Float16)c.y;
    c16[i] = h;
    const vfloat4* p = (const vfloat4*)(vals + 8 * (size_t)i);
    const vfloat4 a = p[0], b = p[1];
    vhalf8 v;
    v[0] = (_Float16)a.x; v[1] = (_Float16)a.y;
    v[2] = (_Float16)a.z; v[3] = (_Float16)a.w;
    v[4] = (_Float16)b.x; v[5] = (_Float16)b.y;
    v[6] = (_Float16)b.z; v[7] = (_Float16)b.w;
    v16[i] = v;
}

__global__ __launch_bounds__(256) void fem_integrate_fp16(
    const vhalf2* __restrict__ c16,      // (N,) quantized coords
    const vhalf8* __restrict__ v16,      // (N,) quantized value rows
    const int*    __restrict__ elements, // (E,3)
    float* __restrict__ out,             // (8,) pre-zeroed
    int E)
{
    float acc[NVALS];
#pragma unroll
    for (int v = 0; v < NVALS; ++v) acc[v] = 0.0f;

    const int stride = gridDim.x * blockDim.x;
    for (int e = blockIdx.x * blockDim.x + threadIdx.x; e < E; e += stride) {
        const int n0 = elements[3 * e + 0];
        const int n1 = elements[3 * e + 1];
        const int n2 = elements[3 * e + 2];

        const vhalf2 h0 = c16[n0];
        const vhalf2 h1 = c16[n1];
        const vhalf2 h2 = c16[n2];
        const float c0x = (float)h0.x, c0y = (float)h0.y;
        const float j00 = (float)h1.x - c0x, j01 = (float)h1.y - c0y;
        const float j10 = (float)h2.x - c0x, j11 = (float)h2.y - c0y;
        const float wdet = (j00 * j11 - j01 * j10) * (1.0f / 6.0f);

        const vhalf8 v0 = v16[n0];
        const vhalf8 v1 = v16[n1];
        const vhalf8 v2 = v16[n2];
#pragma unroll
        for (int k = 0; k < NVALS; ++k) {
            const float s = (float)v0[k] + (float)v1[k] + (float)v2[k];
            acc[k] = fmaf(wdet, s, acc[k]);
        }
    }

    // Wave (64-lane) shuffle reduction.
#pragma unroll
    for (int v = 0; v < NVALS; ++v) {
        float x = acc[v];
        for (int off = 32; off > 0; off >>= 1) x += __shfl_down(x, off, 64);
        acc[v] = x;
    }

    __shared__ float s[4][NVALS];
    const int lane = threadIdx.x & 63;
    const int wave = threadIdx.x >> 6;
    if (lane == 0) {
#pragma unroll
        for (int v = 0; v < NVALS; ++v) s[wave][v] = acc[v];
    }
    __syncthreads();

    if (threadIdx.x < NVALS) {
        const float x = s[0][threadIdx.x] + s[1][threadIdx.x] +
                        s[2][threadIdx.x] + s[3][threadIdx.x];
        atomicAdd(&out[threadIdx.x], x);
    }
}

// Fallback: R1 full-fp32 single-pass (used only if ws is too small).
__global__ __launch_bounds__(256) void fem_integrate_fp32(
    const float* __restrict__ nodal_values,
    const float* __restrict__ coords,
    const int*   __restrict__ elements,
    float* __restrict__ out,
    int E)
{
    float acc[NVALS];
#pragma unroll
    for (int v = 0; v < NVALS; ++v) acc[v] = 0.0f;
    const int stride = gridDim.x * blockDim.x;
    for (int e = blockIdx.x * blockDim.x + threadIdx.x; e < E; e += stride) {
        const int n0 = elements[3 * e + 0];
        const int n1 = elements[3 * e + 1];
        const int n2 = elements[3 * e + 2];
        const float2 c0 = *(const float2*)(coords + 2 * (size_t)n0);
        const float2 c1 = *(const float2*)(coords + 2 * (size_t)n1);
        const float2 c2 = *(const float2*)(coords + 2 * (size_t)n2);
        const float j00 = c1.x - c0.x, j01 = c1.y - c0.y;
        const float j10 = c2.x - c0.x, j11 = c2.y - c0.y;
        const float wdet = (j00 * j11 - j01 * j10) * (1.0f / 6.0f);
        const vfloat4* p0 = (const vfloat4*)(nodal_values + 8 * (size_t)n0);
        const vfloat4* p1 = (const vfloat4*)(nodal_values + 8 * (size_t)n1);
        const vfloat4* p2 = (const vfloat4*)(nodal_values + 8 * (size_t)n2);
        const vfloat4 va = p0[0] + p1[0] + p2[0];
        const vfloat4 vb = p0[1] + p1[1] + p2[1];
        acc[0] = fmaf(wdet, va.x, acc[0]);
        acc[1] = fmaf(wdet, va.y, acc[1]);
        acc[2] = fmaf(wdet, va.z, acc[2]);
        acc[3] = fmaf(wdet, va.w, acc[3]);
        acc[4] = fmaf(wdet, vb.x, acc[4]);
        acc[5] = fmaf(wdet, vb.y, acc[5]);
        acc[6] = fmaf(wdet, vb.z, acc[6]);
        acc[7] = fmaf(wdet, vb.w, acc[7]);
    }
#pragma unroll
    for (int v = 0; v < NVALS; ++v) {
        float x = acc[v];
        for (int off = 32; off > 0; off >>= 1) x += __shfl_down(x, off, 64);
        acc[v] = x;
    }
    __shared__ float s[4][NVALS];
    const int lane = threadIdx.x & 63;
    const int wave = threadIdx.x >> 6;
    if (lane == 0) {
#pragma unroll
        for (int v = 0; v < NVALS; ++v) s[wave][v] = acc[v];
    }
    __syncthreads();
    if (threadIdx.x < NVALS) {
        const float x = s[0][threadIdx.x] + s[1][threadIdx.x] +
                        s[2][threadIdx.x] + s[3][threadIdx.x];
        atomicAdd(&out[threadIdx.x], x);
    }
}

extern "C" void kernel_launch(void* const* d_in, const int* in_sizes, int n_in,
                              void* d_out, int out_size, void* d_ws, size_t ws_size,
                              hipStream_t stream) {
    const float* nodal_values = (const float*)d_in[0];  // (N,8)
    const float* coords       = (const float*)d_in[1];  // (N,2)
    const int*   elements     = (const int*)d_in[2];    // (E,3)
    float* out = (float*)d_out;

    const int N = in_sizes[1] / 2;
    const int E = in_sizes[2] / 3;

    (void)hipMemsetAsync(out, 0, out_size * sizeof(float), stream);

    // ws layout: [0, 4N) bytes = c16 (N x half2), [4N, 4N+16N) = v16 (N x half8).
    const size_t need = 4 * (size_t)N + 16 * (size_t)N;
    if (ws_size >= need) {
        vhalf2* c16 = (vhalf2*)d_ws;
        vhalf8* v16 = (vhalf8*)((char*)d_ws + 4 * (size_t)N);

        const int cblocks = (N + 255) / 256;
        convert_fp16<<<cblocks, 256, 0, stream>>>(coords, nodal_values,
                                                  c16, v16, N);

        fem_integrate_fp16<<<2048, 256, 0, stream>>>(c16, v16, elements,
                                                     out, E);
    } else {
        fem_integrate_fp32<<<2048, 256, 0, stream>>>(nodal_values, coords,
                                                     elements, out, E);
    }
}